// Round 16
// baseline (161.483 us; speedup 1.0000x reference)
//
#include <hip/hip_runtime.h>
#include <hip/hip_fp16.h>
#include <math.h>
#include <float.h>

#define M_G 100000
#define M_PAD 100032         // 1563 * 64
#define NT64 1563            // 64-row gallery tiles
#define N_Q 2048
#define DIM 256
#define NG 3126              // 32-row groups = NT64*2
#define GSTR 3136            // padded group stride (halves) per query row
#define NC4 392              // GSTR/8 uint4 chunks per query row
#define MARGIN 0.009f        // 2*(2^-11 RN) fp16 dot bound + fp16-bmax quant + slack

typedef _Float16 f16x8 __attribute__((ext_vector_type(8)));
typedef float f32x4 __attribute__((ext_vector_type(4)));

// ws layout (bytes)
#define WS_GP 0                        // 1563 * 32768 = 51,216,384
#define WS_QP 51216384                 // 8 * 131072   =  1,048,576
#define WS_BM 52264960                 // 2048*3136*2  = 12,845,056

__device__ inline unsigned pack_h2(float a, float b) {
    __half ha = __float2half(a), hb = __float2half(b);   // RN
    return (unsigned)*(unsigned short*)&ha | ((unsigned)*(unsigned short*)&hb << 16);
}
__device__ inline void gload_lds16(const void* gsrc, void* ldst) {
    __builtin_amdgcn_global_load_lds(
        (const __attribute__((address_space(1))) unsigned int*)gsrc,
        (__attribute__((address_space(3))) unsigned int*)ldst, 16, 0, 0);
}

#define BAR __builtin_amdgcn_s_barrier()
#define VMCNT(n) { asm volatile("s_waitcnt vmcnt(" #n ")" ::: "memory"); \
                   __builtin_amdgcn_sched_barrier(0); }

// Normalize rows, fp32->fp16 (RN), store swizzled LDS-image layout.
// Gallery: 64-row tiles; chunk (mt64*4+kt) of 512 uint4; granule (rl∈[0,64),gg)
// at rl*8 + (gg ^ (rl&7)). Queries: 256-row tiles; chunk (qt*4+kt) of 2048
// uint4, rl∈[0,256). Gallery pad rows (>=M_G) zeroed.
__global__ __launch_bounds__(256) void pack_kernel(
    const float* __restrict__ g, const float* __restrict__ q,
    uint4* __restrict__ gp, uint4* __restrict__ qp)
{
    const int b = blockIdx.x;
    const int w4 = threadIdx.x >> 6, lane = threadIdx.x & 63;
    const bool isg = b < (M_PAD / 4);
    const int row = (isg ? b : b - M_PAD / 4) * 4 + w4;
    const bool real = !isg || row < M_G;
    const float* src = isg ? g + (size_t)row * DIM : q + (size_t)row * DIM;

    float inv = 0.0f;
    if (real) {
        float4 v = ((const float4*)src)[lane];
        float ss = v.x * v.x + v.y * v.y + v.z * v.z + v.w * v.w;
        #pragma unroll
        for (int o = 32; o; o >>= 1) ss += __shfl_xor(ss, o);
        inv = 1.0f / fmaxf(sqrtf(ss), 1e-12f);
    }
    if (lane < 32) {
        uint4 w = make_uint4(0u, 0u, 0u, 0u);
        if (real) {
            float4 a = ((const float4*)src)[lane * 2];
            float4 c = ((const float4*)src)[lane * 2 + 1];
            w.x = pack_h2(a.x * inv, a.y * inv);
            w.y = pack_h2(a.z * inv, a.w * inv);
            w.z = pack_h2(c.x * inv, c.y * inv);
            w.w = pack_h2(c.z * inv, c.w * inv);
        }
        const int kt = lane >> 3, gg = lane & 7;
        if (isg) {
            int mt = row >> 6, rl = row & 63;
            gp[((size_t)mt * 4 + kt) * 512 + rl * 8 + (gg ^ (rl & 7))] = w;
        } else {
            int qt = row >> 8, rl = row & 255;
            qp[((size_t)qt * 4 + kt) * 2048 + rl * 8 + (gg ^ (rl & 7))] = w;
        }
    }
}

#define STAGE32(dstbase, src) { const uint4* s_ = (src); _Pragma("unroll") \
  for (int p_ = 0; p_ < 4; ++p_) \
    gload_lds16(s_ + p_ * 512 + tid, lds + (dstbase) + (p_ * 512 + tid) * 16); }

#define READ_BP(KT, bufbase) { _Pragma("unroll") \
  for (int nj = 0; nj < 4; ++nj) { \
    const char* p_ = lds + (bufbase) + (wc * 64 + nj * 16 + r16) * 128; \
    bR[KT][0][nj] = *(const f16x8*)(p_ + sw0); \
    bR[KT][1][nj] = *(const f16x8*)(p_ + sw1); } }

#define ZERO_ACC(ACC) { _Pragma("unroll") \
  for (int mi = 0; mi < 2; ++mi) _Pragma("unroll") \
    for (int nj = 0; nj < 4; ++nj) ACC[mi][nj] = (f32x4){0.f, 0.f, 0.f, 0.f}; }

#define TILE_MFMA(ACC, curb) { _Pragma("unroll") \
  for (int kt = 0; kt < 4; ++kt) { _Pragma("unroll") \
    for (int kk = 0; kk < 2; ++kk) { \
      const char* p_ = lds + (curb) + kt * 8192 + (wr * 32 + r16) * 128; \
      const int sw_ = kk ? sw1 : sw0; \
      f16x8 a0 = *(const f16x8*)(p_ + sw_); \
      f16x8 a1 = *(const f16x8*)(p_ + 2048 + sw_); \
      _Pragma("unroll") \
      for (int nj = 0; nj < 4; ++nj) { \
        ACC[0][nj] = __builtin_amdgcn_mfma_f32_16x16x32_f16( \
            a0, bR[kt][kk][nj], ACC[0][nj], 0, 0, 0); \
        ACC[1][nj] = __builtin_amdgcn_mfma_f32_16x16x32_f16( \
            a1, bR[kt][kk][nj], ACC[1][nj], 0, 0, 0); } } } }

// per-q max over a finished tile's acc; TT = global tile index
#define EPI(ACC, TT) { \
    float cm_[4] = {-FLT_MAX, -FLT_MAX, -FLT_MAX, -FLT_MAX}; \
    _Pragma("unroll") \
    for (int mi = 0; mi < 2; ++mi) _Pragma("unroll") \
      for (int jj = 0; jj < 4; ++jj) _Pragma("unroll") \
        for (int nj = 0; nj < 4; ++nj) \
          cm_[nj] = fmaxf(cm_[nj], ACC[mi][nj][jj]); \
    const bool padgrp_ = ((TT) * 64 + wr * 32) >= M_G; \
    _Pragma("unroll") \
    for (int nj = 0; nj < 4; ++nj) { \
      float v_ = cm_[nj]; \
      v_ = fmaxf(v_, __shfl_xor(v_, 16)); \
      v_ = fmaxf(v_, __shfl_xor(v_, 32)); \
      if (lane < 16) { \
        int qn_ = qt * 256 + wc * 64 + nj * 16 + lane; \
        __half h_ = __float2half(padgrp_ ? -65504.f : v_); \
        bmaxH[(size_t)qn_ * GSTR + (TT) * 2 + wr] = *(unsigned short*)&h_; \
      } \
    } }

// Phase A: Q-stationary M-streaming fp16 MFMA (R7 geometry: 256 blocks =
// 8 qt x 32 mchunks, 512 thr = 8 waves 2m x 4n, 64-row tiles, 2x32KB dbuf,
// counted vmcnt) + T15 DEFERRED EPILOGUE: tile t's per-q max reduction
// (fmax/shfl/cvt/store, ~1100 cy of VALU+DS that used to sit serially on
// the critical path) now executes in the same barrier region as tile t+1's
// MFMAs, on independent registers -- scheduler and the co-resident wave
// overlap it with the matrix pipe (m114). Ping-pong accA/accB, static
// indices, loop unrolled x2. vmcnt unchanged: 4 stage loads (oldest) +
// 4 deferred stores -> VMCNT(4) waits exactly the loads.
__global__ __launch_bounds__(512, 2) void scoreA_kernel(
    const uint4* __restrict__ gp, const uint4* __restrict__ qp,
    unsigned short* __restrict__ bmaxH)
{
    extern __shared__ char lds[];   // 65536: buf0 [0,32K) | buf1 [32K,64K)

    const int bid = blockIdx.x;
    const int qt = bid >> 5, mc = bid & 31;
    const int nt = (mc < 27) ? 49 : 48;
    const int t0 = (mc < 27) ? mc * 49 : 1323 + (mc - 27) * 48;

    const int tid = threadIdx.x;
    const int wid = tid >> 6, lane = tid & 63;
    const int wr = wid >> 2, wc = wid & 3;          // 2m x 4n wave grid
    const int r16 = lane & 15, rhi = lane >> 4;
    const int sw0 = ((rhi ^ (r16 & 7)) << 4);       // k-granule swizzle, kk=0
    const int sw1 = (((4 + rhi) ^ (r16 & 7)) << 4); // kk=1

    const uint4* qsrc = qp + (size_t)qt * 8192;

    // ---- prologue: load all B (query) fragments into registers ----
    f16x8 bR[4][2][4];
    STAGE32(0,     qsrc + 0 * 2048);
    STAGE32(32768, qsrc + 1 * 2048);
    VMCNT(4); BAR;                   // qp0 ready
    READ_BP(0, 0); BAR;
    STAGE32(0, qsrc + 2 * 2048);
    VMCNT(4); BAR;                   // qp1 ready
    READ_BP(1, 32768); BAR;
    STAGE32(32768, qsrc + 3 * 2048);
    VMCNT(4); BAR;                   // qp2 ready
    READ_BP(2, 0); BAR;
    STAGE32(0, gp + (size_t)t0 * 2048);
    VMCNT(4); BAR;                   // qp3 ready
    READ_BP(3, 32768); BAR;
    VMCNT(0); BAR;                   // A(t0) ready in buf0

    // ---- main loop: deferred-epilogue pipeline ----
    f32x4 accA[2][4], accB[2][4];

    // tile 0 (buf0): stage tile 1 -> buf1; no epilogue yet
    STAGE32(32768, gp + (size_t)(t0 + 1) * 2048);
    ZERO_ACC(accA);
    TILE_MFMA(accA, 0);
    VMCNT(0); BAR;                   // only the 4 loads outstanding

    int t = 1;
    for (; t + 1 < nt; t += 2) {
        // tile t (odd -> buf1): stage t+1 -> buf0; finish tile t-1
        STAGE32(0, gp + (size_t)(t0 + t + 1) * 2048);
        ZERO_ACC(accB);
        TILE_MFMA(accB, 32768);
        EPI(accA, t0 + t - 1);
        VMCNT(4); BAR;
        // tile t+1 (even -> buf0): stage t+2 -> buf1 (if any); finish tile t
        if (t + 2 < nt) {
            STAGE32(32768, gp + (size_t)(t0 + t + 2) * 2048);
            ZERO_ACC(accA);
            TILE_MFMA(accA, 0);
            EPI(accB, t0 + t);
            VMCNT(4); BAR;
        } else {
            ZERO_ACC(accA);
            TILE_MFMA(accA, 0);
            EPI(accB, t0 + t);
        }
    }
    if (t < nt) {
        // leftover odd tile (nt even): buf1, already staged; no more stages
        ZERO_ACC(accB);
        TILE_MFMA(accB, 32768);
        EPI(accA, t0 + t - 1);
        EPI(accB, t0 + t);
    } else {
        // nt odd: last (even) tile sits in accA
        EPI(accA, t0 + nt - 1);
    }
}

// Phase B: s1 scan + candidate collection (32-row groups, fp16 bmax,
// vectorized uint4 loads = 8 halves/load) + exact fp32 rescore with
// recomputed norms; tie-break = lowest index (np.argmax).
__global__ __launch_bounds__(256) void phaseB_kernel(
    const float* __restrict__ q, const float* __restrict__ g,
    const unsigned short* __restrict__ bmaxH,
    const int* __restrict__ cat, const int* __restrict__ shp,
    int* __restrict__ out)
{
    __shared__ __align__(16) float qrow[DIM];
    __shared__ int glist[NG];
    __shared__ int ng;
    __shared__ float smax[4];
    __shared__ float rbs[4];
    __shared__ int rbi[4];

    const int qi = blockIdx.x;
    const int tid = threadIdx.x;
    const int lane = tid & 63, wid = tid >> 6;
    const uint4* bm4 = (const uint4*)(bmaxH + (size_t)qi * GSTR);
    if (tid < 64)
        *(float4*)&qrow[tid * 4] = *(const float4*)(q + (size_t)qi * DIM + tid * 4);
    if (tid == 0) ng = 0;

    // pass 1: s1 = max over valid groups (vectorized, NG-masked)
    float m = -FLT_MAX;
    for (int c = tid; c < NC4; c += 256) {
        uint4 v = bm4[c];
        const __half* hp = (const __half*)&v;
        int base = c * 8;
        #pragma unroll
        for (int j = 0; j < 8; ++j) {
            float f = __half2float(hp[j]);
            if (base + j < NG) m = fmaxf(m, f);
        }
    }
    #pragma unroll
    for (int o = 32; o; o >>= 1) m = fmaxf(m, __shfl_xor(m, o));
    if (lane == 0) smax[wid] = m;
    __syncthreads();
    const float thr = fmaxf(fmaxf(smax[0], smax[1]), fmaxf(smax[2], smax[3])) - MARGIN;

    // pass 2: collect candidate groups (vectorized)
    for (int c = tid; c < NC4; c += 256) {
        uint4 v = bm4[c];
        const __half* hp = (const __half*)&v;
        int base = c * 8;
        #pragma unroll
        for (int j = 0; j < 8; ++j) {
            if (base + j < NG && __half2float(hp[j]) >= thr)
                glist[atomicAdd(&ng, 1)] = base + j;
        }
    }
    __syncthreads();

    float bs = -FLT_MAX;
    int bi = 0x7fffffff;
    const int r = tid >> 3, p = tid & 7;    // 32 rows x 8 dim-slices
    const int n = ng;
    for (int i = 0; i < n; ++i) {
        int mm = glist[i] * 32 + r;
        if (mm < M_G) {
            const float* grow = g + (size_t)mm * DIM + p * 32;
            const float* qr = qrow + p * 32;
            float s = 0.f, ssq = 0.f;
            #pragma unroll
            for (int jj = 0; jj < 8; ++jj) {
                float4 gv = *(const float4*)(grow + jj * 4);
                float4 qv = *(const float4*)(qr + jj * 4);
                s += gv.x * qv.x + gv.y * qv.y + gv.z * qv.z + gv.w * qv.w;
                ssq += gv.x * gv.x + gv.y * gv.y + gv.z * gv.z + gv.w * gv.w;
            }
            s += __shfl_xor(s, 1);  s += __shfl_xor(s, 2);  s += __shfl_xor(s, 4);
            ssq += __shfl_xor(ssq, 1); ssq += __shfl_xor(ssq, 2); ssq += __shfl_xor(ssq, 4);
            s *= 1.0f / fmaxf(sqrtf(ssq), 1e-12f);
            if (p == 0 && (s > bs || (s == bs && mm < bi))) { bs = s; bi = mm; }
        }
    }
    #pragma unroll
    for (int o = 1; o < 64; o <<= 1) {
        float os = __shfl_xor(bs, o);
        int oi = __shfl_xor(bi, o);
        if (os > bs || (os == bs && oi < bi)) { bs = os; bi = oi; }
    }
    if (lane == 0) { rbs[wid] = bs; rbi[wid] = bi; }
    __syncthreads();
    if (tid == 0) {
        #pragma unroll
        for (int ww = 1; ww < 4; ++ww)
            if (rbs[ww] > bs || (rbs[ww] == bs && rbi[ww] < bi)) { bs = rbs[ww]; bi = rbi[ww]; }
        out[qi] = cat[bi];
        out[N_Q + qi] = shp[bi];
    }
}

extern "C" void kernel_launch(void* const* d_in, const int* in_sizes, int n_in,
                              void* d_out, int out_size, void* d_ws, size_t ws_size,
                              hipStream_t stream) {
    const float* q = (const float*)d_in[0];    // [2048,256] fp32
    const float* g = (const float*)d_in[1];    // [100000,256] fp32
    const int* cat = (const int*)d_in[2];      // [100000] int32
    const int* shp = (const int*)d_in[3];      // [100000] int32
    int* out = (int*)d_out;                    // [2048 cat | 2048 shape] int32

    char* ws = (char*)d_ws;
    uint4* gp             = (uint4*)(ws + WS_GP);
    uint4* qp             = (uint4*)(ws + WS_QP);
    unsigned short* bmaxH = (unsigned short*)(ws + WS_BM);

    hipFuncSetAttribute((const void*)scoreA_kernel,
                        hipFuncAttributeMaxDynamicSharedMemorySize, 65536);

    pack_kernel<<<M_PAD / 4 + N_Q / 4, 256, 0, stream>>>(g, q, gp, qp);
    scoreA_kernel<<<256, 512, 65536, stream>>>(gp, qp, bmaxH);
    phaseB_kernel<<<N_Q, 256, 0, stream>>>(q, g, bmaxH, cat, shp, out);
}

// Round 17
// 152.048 us; speedup vs baseline: 1.0621x; 1.0621x over previous
//
#include <hip/hip_runtime.h>
#include <hip/hip_fp16.h>
#include <math.h>
#include <float.h>

#define M_G 100000
#define M_PAD 100032         // 1563 * 64
#define NT64 1563            // 64-row gallery tiles
#define N_Q 2048
#define DIM 256
#define NG 3126              // 32-row groups = NT64*2
#define GSTR 3136            // padded group stride (halves) per query row
#define NC4 392              // GSTR/8 uint4 chunks per query row
#define MARGIN 0.004f        // bound: 2^-10 conv + 2^-12 fp16-bmax quant ~= 0.00125; 3.2x headroom

typedef _Float16 f16x8 __attribute__((ext_vector_type(8)));
typedef float f32x4 __attribute__((ext_vector_type(4)));

// ws layout (bytes)
#define WS_GP 0                        // 1563 * 32768 = 51,216,384
#define WS_QP 51216384                 // 8 * 131072   =  1,048,576
#define WS_BM 52264960                 // 2048*3136*2  = 12,845,056

__device__ inline unsigned pack_h2(float a, float b) {
    __half ha = __float2half(a), hb = __float2half(b);   // RN
    return (unsigned)*(unsigned short*)&ha | ((unsigned)*(unsigned short*)&hb << 16);
}
__device__ inline void gload_lds16(const void* gsrc, void* ldst) {
    __builtin_amdgcn_global_load_lds(
        (const __attribute__((address_space(1))) unsigned int*)gsrc,
        (__attribute__((address_space(3))) unsigned int*)ldst, 16, 0, 0);
}

#define BAR __builtin_amdgcn_s_barrier()
#define VMCNT(n) { asm volatile("s_waitcnt vmcnt(" #n ")" ::: "memory"); \
                   __builtin_amdgcn_sched_barrier(0); }

// Normalize rows, fp32->fp16 (RN), store swizzled LDS-image layout.
// Gallery: 64-row tiles; chunk (mt64*4+kt) of 512 uint4; granule (rl∈[0,64),gg)
// at rl*8 + (gg ^ (rl&7)). Queries: 256-row tiles; chunk (qt*4+kt) of 2048
// uint4, rl∈[0,256). Gallery pad rows (>=M_G) zeroed.
__global__ __launch_bounds__(256) void pack_kernel(
    const float* __restrict__ g, const float* __restrict__ q,
    uint4* __restrict__ gp, uint4* __restrict__ qp)
{
    const int b = blockIdx.x;
    const int w4 = threadIdx.x >> 6, lane = threadIdx.x & 63;
    const bool isg = b < (M_PAD / 4);
    const int row = (isg ? b : b - M_PAD / 4) * 4 + w4;
    const bool real = !isg || row < M_G;
    const float* src = isg ? g + (size_t)row * DIM : q + (size_t)row * DIM;

    float inv = 0.0f;
    if (real) {
        float4 v = ((const float4*)src)[lane];
        float ss = v.x * v.x + v.y * v.y + v.z * v.z + v.w * v.w;
        #pragma unroll
        for (int o = 32; o; o >>= 1) ss += __shfl_xor(ss, o);
        inv = 1.0f / fmaxf(sqrtf(ss), 1e-12f);
    }
    if (lane < 32) {
        uint4 w = make_uint4(0u, 0u, 0u, 0u);
        if (real) {
            float4 a = ((const float4*)src)[lane * 2];
            float4 c = ((const float4*)src)[lane * 2 + 1];
            w.x = pack_h2(a.x * inv, a.y * inv);
            w.y = pack_h2(a.z * inv, a.w * inv);
            w.z = pack_h2(c.x * inv, c.y * inv);
            w.w = pack_h2(c.z * inv, c.w * inv);
        }
        const int kt = lane >> 3, gg = lane & 7;
        if (isg) {
            int mt = row >> 6, rl = row & 63;
            gp[((size_t)mt * 4 + kt) * 512 + rl * 8 + (gg ^ (rl & 7))] = w;
        } else {
            int qt = row >> 8, rl = row & 255;
            qp[((size_t)qt * 4 + kt) * 2048 + rl * 8 + (gg ^ (rl & 7))] = w;
        }
    }
}

#define STAGE32(dstbase, src) { const uint4* s_ = (src); _Pragma("unroll") \
  for (int p_ = 0; p_ < 4; ++p_) \
    gload_lds16(s_ + p_ * 512 + tid, lds + (dstbase) + (p_ * 512 + tid) * 16); }

#define READ_BP(KT, bufbase) { _Pragma("unroll") \
  for (int nj = 0; nj < 4; ++nj) { \
    const char* p_ = lds + (bufbase) + (wc * 64 + nj * 16 + r16) * 128; \
    bR[KT][0][nj] = *(const f16x8*)(p_ + sw0); \
    bR[KT][1][nj] = *(const f16x8*)(p_ + sw1); } }

// Phase A: Q-stationary M-streaming fp16 MFMA (R7/R15 geometry: 256 blocks =
// 8 qt x 32 mchunks, 512 thr = 8 waves 2m x 4n, 64-row tiles, 2x32KB dbuf,
// counted vmcnt) + ASYMMETRIC WAVE PRIORITY: even waves run at prio 1 for the
// whole main loop, so the two block-locked waves on each SIMD drift into
// anti-phase (one in its ds_read/latency window while the other occupies the
// MFMA pipe) instead of hitting both pipes in lockstep. T5's role-diversity
// prerequisite, created by construction (m190's null was symmetric prio).
__global__ __launch_bounds__(512, 2) void scoreA_kernel(
    const uint4* __restrict__ gp, const uint4* __restrict__ qp,
    unsigned short* __restrict__ bmaxH)
{
    extern __shared__ char lds[];   // 65536: buf0 [0,32K) | buf1 [32K,64K)

    const int bid = blockIdx.x;
    const int qt = bid >> 5, mc = bid & 31;
    const int nt = (mc < 27) ? 49 : 48;
    const int t0 = (mc < 27) ? mc * 49 : 1323 + (mc - 27) * 48;

    const int tid = threadIdx.x;
    const int wid = tid >> 6, lane = tid & 63;
    const int wr = wid >> 2, wc = wid & 3;          // 2m x 4n wave grid
    const int r16 = lane & 15, rhi = lane >> 4;
    const int sw0 = ((rhi ^ (r16 & 7)) << 4);       // k-granule swizzle, kk=0
    const int sw1 = (((4 + rhi) ^ (r16 & 7)) << 4); // kk=1

    const uint4* qsrc = qp + (size_t)qt * 8192;

    // ---- prologue: load all B (query) fragments into registers ----
    f16x8 bR[4][2][4];
    STAGE32(0,     qsrc + 0 * 2048);
    STAGE32(32768, qsrc + 1 * 2048);
    VMCNT(4); BAR;                   // qp0 ready
    READ_BP(0, 0); BAR;
    STAGE32(0, qsrc + 2 * 2048);
    VMCNT(4); BAR;                   // qp1 ready
    READ_BP(1, 32768); BAR;
    STAGE32(32768, qsrc + 3 * 2048);
    VMCNT(4); BAR;                   // qp2 ready
    READ_BP(2, 0); BAR;
    STAGE32(0, gp + (size_t)t0 * 2048);
    VMCNT(4); BAR;                   // qp3 ready
    READ_BP(3, 32768); BAR;
    VMCNT(0); BAR;                   // A(t0) ready in buf0

    // asymmetric priority: even waves lead, odd waves trail -> anti-phase
    if ((wid & 1) == 0) __builtin_amdgcn_s_setprio(1);

    // ---- main loop: stream gallery tiles ----
    for (int t = 0; t < nt; ++t) {
        const int mtile = t0 + t;
        const int cur = (t & 1) << 15;
        const int nxt = cur ^ 32768;
        if (t + 1 < nt) STAGE32(nxt, gp + (size_t)(mtile + 1) * 2048);

        f32x4 acc[2][4];
        #pragma unroll
        for (int mi = 0; mi < 2; ++mi)
            #pragma unroll
            for (int nj = 0; nj < 4; ++nj) acc[mi][nj] = (f32x4){0.f, 0.f, 0.f, 0.f};

        #pragma unroll
        for (int kt = 0; kt < 4; ++kt) {
            #pragma unroll
            for (int kk = 0; kk < 2; ++kk) {
                const char* p_ = lds + cur + kt * 8192 + (wr * 32 + r16) * 128;
                const int sw = kk ? sw1 : sw0;
                f16x8 a0 = *(const f16x8*)(p_ + sw);
                f16x8 a1 = *(const f16x8*)(p_ + 2048 + sw);
                #pragma unroll
                for (int nj = 0; nj < 4; ++nj) {
                    acc[0][nj] = __builtin_amdgcn_mfma_f32_16x16x32_f16(
                        a0, bR[kt][kk][nj], acc[0][nj], 0, 0, 0);
                    acc[1][nj] = __builtin_amdgcn_mfma_f32_16x16x32_f16(
                        a1, bR[kt][kk][nj], acc[1][nj], 0, 0, 0);
                }
            }
        }

        // epilogue: per-q max over this wave's two 16-row frags (32-row group)
        float cm[4] = {-FLT_MAX, -FLT_MAX, -FLT_MAX, -FLT_MAX};
        #pragma unroll
        for (int mi = 0; mi < 2; ++mi)
            #pragma unroll
            for (int jj = 0; jj < 4; ++jj)
                #pragma unroll
                for (int nj = 0; nj < 4; ++nj)
                    cm[nj] = fmaxf(cm[nj], acc[mi][nj][jj]);
        // pad-safety: the last tile's wr=1 group is exactly rows >= M_G
        const bool padgrp = (mtile * 64 + wr * 32) >= M_G;
        #pragma unroll
        for (int nj = 0; nj < 4; ++nj) {
            float v = cm[nj];
            v = fmaxf(v, __shfl_xor(v, 16));
            v = fmaxf(v, __shfl_xor(v, 32));
            if (lane < 16) {
                int qn = qt * 256 + wc * 64 + nj * 16 + lane;
                __half h = __float2half(padgrp ? -65504.f : v);
                bmaxH[(size_t)qn * GSTR + mtile * 2 + wr] = *(unsigned short*)&h;
            }
        }
        // outstanding: 4 loads (oldest) + 4 stores -> VMCNT(4) = loads done
        if (t + 1 < nt) { VMCNT(4); BAR; }
    }
}

// Phase B: s1 scan + candidate collection (32-row groups, fp16 bmax,
// vectorized uint4 loads = 8 halves/load) + exact fp32 rescore with
// recomputed norms; tie-break = lowest index (np.argmax).
__global__ __launch_bounds__(256) void phaseB_kernel(
    const float* __restrict__ q, const float* __restrict__ g,
    const unsigned short* __restrict__ bmaxH,
    const int* __restrict__ cat, const int* __restrict__ shp,
    int* __restrict__ out)
{
    __shared__ __align__(16) float qrow[DIM];
    __shared__ int glist[NG];
    __shared__ int ng;
    __shared__ float smax[4];
    __shared__ float rbs[4];
    __shared__ int rbi[4];

    const int qi = blockIdx.x;
    const int tid = threadIdx.x;
    const int lane = tid & 63, wid = tid >> 6;
    const uint4* bm4 = (const uint4*)(bmaxH + (size_t)qi * GSTR);
    if (tid < 64)
        *(float4*)&qrow[tid * 4] = *(const float4*)(q + (size_t)qi * DIM + tid * 4);
    if (tid == 0) ng = 0;

    // pass 1: s1 = max over valid groups (vectorized, NG-masked)
    float m = -FLT_MAX;
    for (int c = tid; c < NC4; c += 256) {
        uint4 v = bm4[c];
        const __half* hp = (const __half*)&v;
        int base = c * 8;
        #pragma unroll
        for (int j = 0; j < 8; ++j) {
            float f = __half2float(hp[j]);
            if (base + j < NG) m = fmaxf(m, f);
        }
    }
    #pragma unroll
    for (int o = 32; o; o >>= 1) m = fmaxf(m, __shfl_xor(m, o));
    if (lane == 0) smax[wid] = m;
    __syncthreads();
    const float thr = fmaxf(fmaxf(smax[0], smax[1]), fmaxf(smax[2], smax[3])) - MARGIN;

    // pass 2: collect candidate groups (vectorized)
    for (int c = tid; c < NC4; c += 256) {
        uint4 v = bm4[c];
        const __half* hp = (const __half*)&v;
        int base = c * 8;
        #pragma unroll
        for (int j = 0; j < 8; ++j) {
            if (base + j < NG && __half2float(hp[j]) >= thr)
                glist[atomicAdd(&ng, 1)] = base + j;
        }
    }
    __syncthreads();

    float bs = -FLT_MAX;
    int bi = 0x7fffffff;
    const int r = tid >> 3, p = tid & 7;    // 32 rows x 8 dim-slices
    const int n = ng;
    for (int i = 0; i < n; ++i) {
        int mm = glist[i] * 32 + r;
        if (mm < M_G) {
            const float* grow = g + (size_t)mm * DIM + p * 32;
            const float* qr = qrow + p * 32;
            float s = 0.f, ssq = 0.f;
            #pragma unroll
            for (int jj = 0; jj < 8; ++jj) {
                float4 gv = *(const float4*)(grow + jj * 4);
                float4 qv = *(const float4*)(qr + jj * 4);
                s += gv.x * qv.x + gv.y * qv.y + gv.z * qv.z + gv.w * qv.w;
                ssq += gv.x * gv.x + gv.y * gv.y + gv.z * gv.z + gv.w * gv.w;
            }
            s += __shfl_xor(s, 1);  s += __shfl_xor(s, 2);  s += __shfl_xor(s, 4);
            ssq += __shfl_xor(ssq, 1); ssq += __shfl_xor(ssq, 2); ssq += __shfl_xor(ssq, 4);
            s *= 1.0f / fmaxf(sqrtf(ssq), 1e-12f);
            if (p == 0 && (s > bs || (s == bs && mm < bi))) { bs = s; bi = mm; }
        }
    }
    #pragma unroll
    for (int o = 1; o < 64; o <<= 1) {
        float os = __shfl_xor(bs, o);
        int oi = __shfl_xor(bi, o);
        if (os > bs || (os == bs && oi < bi)) { bs = os; bi = oi; }
    }
    if (lane == 0) { rbs[wid] = bs; rbi[wid] = bi; }
    __syncthreads();
    if (tid == 0) {
        #pragma unroll
        for (int ww = 1; ww < 4; ++ww)
            if (rbs[ww] > bs || (rbs[ww] == bs && rbi[ww] < bi)) { bs = rbs[ww]; bi = rbi[ww]; }
        out[qi] = cat[bi];
        out[N_Q + qi] = shp[bi];
    }
}

extern "C" void kernel_launch(void* const* d_in, const int* in_sizes, int n_in,
                              void* d_out, int out_size, void* d_ws, size_t ws_size,
                              hipStream_t stream) {
    const float* q = (const float*)d_in[0];    // [2048,256] fp32
    const float* g = (const float*)d_in[1];    // [100000,256] fp32
    const int* cat = (const int*)d_in[2];      // [100000] int32
    const int* shp = (const int*)d_in[3];      // [100000] int32
    int* out = (int*)d_out;                    // [2048 cat | 2048 shape] int32

    char* ws = (char*)d_ws;
    uint4* gp             = (uint4*)(ws + WS_GP);
    uint4* qp             = (uint4*)(ws + WS_QP);
    unsigned short* bmaxH = (unsigned short*)(ws + WS_BM);

    hipFuncSetAttribute((const void*)scoreA_kernel,
                        hipFuncAttributeMaxDynamicSharedMemorySize, 65536);

    pack_kernel<<<M_PAD / 4 + N_Q / 4, 256, 0, stream>>>(g, q, gp, qp);
    scoreA_kernel<<<256, 512, 65536, stream>>>(gp, qp, bmaxH);
    phaseB_kernel<<<N_Q, 256, 0, stream>>>(q, g, bmaxH, cat, shp, out);
}